// Round 17
// baseline (67.067 us; speedup 1.0000x reference)
//
#include <hip/hip_runtime.h>
#include <hip/hip_bf16.h>
#include <stdint.h>

#define N_NODES   50000
#define K_DIM     128
#define OUT_DIM   32
#define N_EDGES   1600000
#define NBKT      782                         // 64-node coarse buckets
#define CAP       3072                        // fixed window stride (mean 2046 + 22 sigma)
#define AFIT      16                          // edges per thread in fill
#define FB        ((N_EDGES + 256*AFIT - 1) / (256*AFIT))   // 391 fill blocks
#define GB        ((N_NODES + 63) / 64)                     // 782 gemm blocks (64 rows each)

// -------- K0: zero the 782 bucket cursors (tiny) ----------------------------
__global__ __launch_bounds__(256) void zero_cursor(int* __restrict__ cursor) {
    for (int i = threadIdx.x; i < NBKT; i += 256) cursor[i] = 0;
}

// -------- K1: FUSED gemm + fill (data-independent roles, co-resident) -------
// blocks [0,FB): fill edges into fixed-stride bucket windows
// blocks [FB,FB+GB): h = x @ W -> bf16; 64 rows/block, 4 rows x 2 cols/thread
__global__ __launch_bounds__(256) void gemm_fill(const float* __restrict__ x,
                                                 const float* __restrict__ w,
                                                 __hip_bfloat16* __restrict__ h,
                                                 const int*   __restrict__ esrc,
                                                 const int*   __restrict__ edst,
                                                 const float* __restrict__ ew,
                                                 int*         __restrict__ cursor,
                                                 uint64_t*    __restrict__ pairs) {
    __shared__ __align__(16) char smem[50176];   // 16K W + 64x33 float4 x-tile
    const int t = threadIdx.x;

    if (blockIdx.x < FB) {
        // ---------------- fill role (uses first 8 KB) ----------------
        int* cnt   = (int*)smem;               // 782 ints
        int* wbase = ((int*)smem) + 1024;      // 782 ints
        for (int i = t; i < NBKT; i += 256) cnt[i] = 0;
        __syncthreads();

        uint32_t lo[AFIT], hi[AFIT];
        uint16_t rk[AFIT];
        const int base = blockIdx.x * 256 * AFIT;
        #pragma unroll
        for (int k = 0; k < AFIT; ++k) {
            const int e = base + k * 256 + t;
            if (e < N_EDGES) {
                const uint32_t s = (uint32_t)esrc[e];
                const uint32_t d = (uint32_t)edst[e];
                lo[k] = (d << 16) | s;         // dst:16 | src:16
                hi[k] = __float_as_uint(ew[e]);
                rk[k] = (uint16_t)atomicAdd(&cnt[d >> 6], 1);   // count AND rank
            } else {
                lo[k] = 0xffffffffu;
            }
        }
        __syncthreads();
        for (int i = t; i < NBKT; i += 256) {
            const int c = cnt[i];
            if (c) wbase[i] = atomicAdd(&cursor[i], c);
        }
        __syncthreads();
        #pragma unroll
        for (int k = 0; k < AFIT; ++k) {
            if (lo[k] != 0xffffffffu) {
                const int b   = (int)(lo[k] >> 22);             // dst >> 6
                const int pos = wbase[b] + (int)rk[k];
                if (pos < CAP)                                  // overflow guard (P ~ 0)
                    pairs[(size_t)b * CAP + pos] = ((uint64_t)hi[k] << 32) | lo[k];
            }
        }
    } else {
        // ---------------- gemm role ----------------
        float*  wlds = (float*)smem;                    // W [128][32] f32 = 16 KB
        float4* wl4  = (float4*)smem;
        float4* xl4  = (float4*)(smem + 16384);         // x tile [64][33] float4 (+pad)

        // stage W: 1024 float4, coalesced
        const float4* wg4 = reinterpret_cast<const float4*>(w);
        #pragma unroll
        for (int i = 0; i < 4; ++i) wl4[i * 256 + t] = wg4[i * 256 + t];

        // stage x tile: 64 rows = 2048 float4, coalesced read, padded LDS write
        const int row0 = (blockIdx.x - FB) * 64;
        const long long gbase4 = (long long)row0 * (K_DIM / 4);
        const long long gmax4  = (long long)N_NODES * (K_DIM / 4);
        const float4* xg4 = reinterpret_cast<const float4*>(x);
        #pragma unroll
        for (int i = 0; i < 8; ++i) {
            const int idx = i * 256 + t;               // 0..2047
            const int row = idx >> 5;                  // /32
            const int k4  = idx & 31;
            const long long gi = gbase4 + idx;
            xl4[row * 33 + k4] = (gi < gmax4) ? xg4[gi]
                                              : make_float4(0.f, 0.f, 0.f, 0.f);
        }
        __syncthreads();

        const int cg = t & 15;                 // col pair 2cg, 2cg+1
        const int rg = t >> 4;                 // 16 row-groups of 4 rows
        const float2* w2 = reinterpret_cast<const float2*>(wlds);

        float acc[4][2] = {{0.f,0.f},{0.f,0.f},{0.f,0.f},{0.f,0.f}};
        #pragma unroll 4
        for (int k4 = 0; k4 < K_DIM / 4; ++k4) {
            const int k = k4 * 4;
            const float2 wv0 = w2[(k + 0) * 16 + cg];
            const float2 wv1 = w2[(k + 1) * 16 + cg];
            const float2 wv2 = w2[(k + 2) * 16 + cg];
            const float2 wv3 = w2[(k + 3) * 16 + cg];
            #pragma unroll
            for (int r = 0; r < 4; ++r) {
                const float4 xv = xl4[(rg * 4 + r) * 33 + k4];
                acc[r][0] += xv.x * wv0.x + xv.y * wv1.x + xv.z * wv2.x + xv.w * wv3.x;
                acc[r][1] += xv.x * wv0.y + xv.y * wv1.y + xv.z * wv2.y + xv.w * wv3.y;
            }
        }
        uint32_t* h32 = reinterpret_cast<uint32_t*>(h);
        #pragma unroll
        for (int r = 0; r < 4; ++r) {
            const int row = row0 + rg * 4 + r;
            if (row < N_NODES) {
                __hip_bfloat16 b0 = __float2bfloat16(acc[r][0]);
                __hip_bfloat16 b1 = __float2bfloat16(acc[r][1]);
                const uint32_t u0 = *reinterpret_cast<uint16_t*>(&b0);
                const uint32_t u1 = *reinterpret_cast<uint16_t*>(&b1);
                h32[row * 16 + cg] = u0 | (u1 << 16);   // 2 bf16 cols packed
            }
        }
    }
}

// -------- K2: sort+pull — single pairs read, reg ranks, wave-parallel scan --
__global__ __launch_bounds__(512) void sort_pull(const int*      __restrict__ cursor,
                                                 const uint64_t* __restrict__ pairs,
                                                 const __hip_bfloat16* __restrict__ h,
                                                 float*          __restrict__ out) {
    __shared__ uint64_t stg[CAP];             // 24 KB
    __shared__ int lcnt[64];
    __shared__ int loff[65];
    const int b    = blockIdx.x;
    const int t    = threadIdx.x;
    const size_t beg = (size_t)b * CAP;
    const int cnt  = min(cursor[b], CAP);
    const int wv   = t >> 6;                  // 8 waves
    const int lane = t & 63;
    const int col  = lane & 31;
    const int half = lane >> 5;

    if (t < 64) lcnt[t] = 0;
    __syncthreads();

    // single coalesced read + rank capture (static 6-slot unroll: CAP = 6*512)
    uint64_t pl[6];
    int      pr[6];                           // (node<<12)|rank, or -1
    #pragma unroll
    for (int k = 0; k < 6; ++k) {
        const int i = t + k * 512;
        if (i < cnt) {
            const uint64_t p = pairs[beg + i];
            const int nl = (int)((p >> 16) & 63);
            pl[k] = p;
            pr[k] = (nl << 12) | atomicAdd(&lcnt[nl], 1);
        } else {
            pr[k] = -1;
        }
    }
    __syncthreads();
    if (t < 64) {                             // wave-parallel exclusive scan
        const int v = lcnt[t];
        int p = v;
        #pragma unroll
        for (int d = 1; d < 64; d <<= 1) {
            const int n = __shfl_up(p, d, 64);
            if (t >= d) p += n;
        }
        loff[t] = p - v;                      // exclusive prefix
        if (t == 63) loff[64] = p;            // total
    }
    __syncthreads();
    #pragma unroll
    for (int k = 0; k < 6; ++k) {
        if (pr[k] >= 0)
            stg[loff[pr[k] >> 12] + (pr[k] & 0xfff)] = pl[k];
    }
    __syncthreads();

    // pull: wave wv owns local nodes wv*8..wv*8+7
    for (int nl = wv * 8; nl < wv * 8 + 8; ++nl) {
        const int node = (b << 6) + nl;
        if (node >= N_NODES) break;
        const int jb = loff[nl], je = loff[nl + 1];
        float acc = 0.f;
        int j = jb + half;
        for (; j + 6 < je; j += 8) {
            const uint64_t p0 = stg[j];
            const uint64_t p1 = stg[j + 2];
            const uint64_t p2 = stg[j + 4];
            const uint64_t p3 = stg[j + 6];
            const float a0 = __bfloat162float(h[(size_t)(p0 & 0xffffu) * OUT_DIM + col]);
            const float a1 = __bfloat162float(h[(size_t)(p1 & 0xffffu) * OUT_DIM + col]);
            const float a2 = __bfloat162float(h[(size_t)(p2 & 0xffffu) * OUT_DIM + col]);
            const float a3 = __bfloat162float(h[(size_t)(p3 & 0xffffu) * OUT_DIM + col]);
            acc += __uint_as_float((uint32_t)(p0 >> 32)) * a0;
            acc += __uint_as_float((uint32_t)(p1 >> 32)) * a1;
            acc += __uint_as_float((uint32_t)(p2 >> 32)) * a2;
            acc += __uint_as_float((uint32_t)(p3 >> 32)) * a3;
        }
        for (; j < je; j += 2) {
            const uint64_t p = stg[j];
            acc += __uint_as_float((uint32_t)(p >> 32)) *
                   __bfloat162float(h[(size_t)(p & 0xffffu) * OUT_DIM + col]);
        }
        acc += __shfl_xor(acc, 32, 64);
        if (half == 0) out[(size_t)node * OUT_DIM + col] = acc;
    }
}

// -------- fallback path kernels (ws too small): plain gemm + atomic scatter -
__global__ __launch_bounds__(256) void gemm_only(const float* __restrict__ x,
                                                 const float* __restrict__ w,
                                                 __hip_bfloat16* __restrict__ h) {
    __shared__ float wlds[K_DIM * OUT_DIM];
    const int t = threadIdx.x;
    #pragma unroll
    for (int i = 0; i < (K_DIM * OUT_DIM) / 256; ++i)
        wlds[i * 256 + t] = w[i * 256 + t];
    __syncthreads();
    const int row = blockIdx.x * 8 + (t >> 5);
    const int col = t & 31;
    if (row >= N_NODES) return;
    const float4* x4 = reinterpret_cast<const float4*>(x + (size_t)row * K_DIM);
    float acc = 0.f;
    #pragma unroll
    for (int k4 = 0; k4 < K_DIM / 4; ++k4) {
        float4 xv = x4[k4];
        const int k = k4 * 4;
        acc += xv.x * wlds[(k + 0) * OUT_DIM + col] + xv.y * wlds[(k + 1) * OUT_DIM + col]
             + xv.z * wlds[(k + 2) * OUT_DIM + col] + xv.w * wlds[(k + 3) * OUT_DIM + col];
    }
    h[(size_t)row * OUT_DIM + col] = __float2bfloat16(acc);
}

__global__ __launch_bounds__(256) void scatter_kernel(const int*   __restrict__ esrc,
                                                      const int*   __restrict__ edst,
                                                      const float* __restrict__ ew,
                                                      const __hip_bfloat16* __restrict__ h,
                                                      float*       out) {
    const long long gid = (long long)blockIdx.x * blockDim.x + threadIdx.x;
    const int e   = (int)(gid >> 5);
    const int col = (int)(gid & 31);
    if (e >= N_EDGES) return;
    atomicAdd(out + (size_t)edst[e] * OUT_DIM + col,
              ew[e] * __bfloat162float(h[(size_t)esrc[e] * OUT_DIM + col]));
}

extern "C" void kernel_launch(void* const* d_in, const int* in_sizes, int n_in,
                              void* d_out, int out_size, void* d_ws, size_t ws_size,
                              hipStream_t stream) {
    const float* x    = (const float*)d_in[0];
    const float* w    = (const float*)d_in[1];
    const int*   esrc = (const int*)d_in[2];
    const int*   edst = (const int*)d_in[3];
    const float* ew   = (const float*)d_in[4];
    float*       out  = (float*)d_out;

    const size_t PAIRS_B = (size_t)NBKT * CAP * 8;         // 19,218,432
    const size_t H_B     = (size_t)N_NODES * OUT_DIM * 2;  //  3,200,000 (bf16)
    const size_t CUR_B   = (size_t)NBKT * 4;               //      3,128
    const size_t REQ     = PAIRS_B + H_B + CUR_B;

    uint64_t*        pairs  = (uint64_t*)d_ws;
    __hip_bfloat16*  h      = (__hip_bfloat16*)((char*)d_ws + PAIRS_B);
    int*             cursor = (int*)((char*)d_ws + PAIRS_B + H_B);

    if (ws_size >= REQ) {
        zero_cursor<<<1, 256, 0, stream>>>(cursor);
        gemm_fill<<<FB + GB, 256, 0, stream>>>(x, w, h, esrc, edst, ew, cursor, pairs);
        sort_pull<<<NBKT, 512, 0, stream>>>(cursor, pairs, h, out);
    } else {
        __hip_bfloat16* hf = (__hip_bfloat16*)d_ws;
        (void)hipMemsetAsync(d_out, 0, (size_t)out_size * sizeof(float), stream);
        gemm_only<<<(N_NODES + 7) / 8, 256, 0, stream>>>(x, w, hf);
        const long long total = (long long)N_EDGES * OUT_DIM;
        scatter_kernel<<<(int)((total + 255) / 256), 256, 0, stream>>>(esrc, edst, ew, hf, out);
    }
}

// Round 18
// 63.407 us; speedup vs baseline: 1.0577x; 1.0577x over previous
//
#include <hip/hip_runtime.h>
#include <hip/hip_bf16.h>
#include <stdint.h>

#define N_NODES   50000
#define K_DIM     128
#define OUT_DIM   32
#define N_EDGES   1600000
#define NBKT      782                         // 64-node coarse buckets
#define CAP       3072                        // fixed window stride (mean 2046 + 22 sigma)
#define AFIT      16                          // edges per thread in fill (4096/block)
#define FB        ((N_EDGES + 256*AFIT - 1) / (256*AFIT))   // 391 fill blocks
#define GB        ((N_NODES + 63) / 64)                     // 782 gemm blocks

// -------- K0: zero the 782 bucket cursors (tiny) ----------------------------
__global__ __launch_bounds__(256) void zero_cursor(int* __restrict__ cursor) {
    for (int i = threadIdx.x; i < NBKT; i += 256) cursor[i] = 0;
}

// -------- K1: FUSED gemm + fill -----------------------------------------------
// fill role: stage 4096 edges in LDS sorted by bucket, then LINE-MERGED writes
// gemm role: h = x @ W -> bf16; 64 rows/block, 4 rows x 2 cols/thread (R17)
__global__ __launch_bounds__(256) void gemm_fill(const float* __restrict__ x,
                                                 const float* __restrict__ w,
                                                 __hip_bfloat16* __restrict__ h,
                                                 const int*   __restrict__ esrc,
                                                 const int*   __restrict__ edst,
                                                 const float* __restrict__ ew,
                                                 int*         __restrict__ cursor,
                                                 uint64_t*    __restrict__ pairs) {
    __shared__ __align__(16) char smem[50176];
    const int t = threadIdx.x;

    if (blockIdx.x < FB) {
        // ---------------- fill role: LDS bucket-sort then coalesced write ----
        int*      cnt   = (int*)smem;                       // [800] counts -> boff (in place)
        int*      wbase = (int*)(smem + 3200);              // [800]
        int*      scr   = (int*)(smem + 6400);              // [256] scan scratch
        uint16_t* rkA   = (uint16_t*)(smem + 7424);         // [4096] ranks
        uint64_t* stg   = (uint64_t*)(smem + 17408);        // [4096] sorted pairs (32 KB)

        for (int i = t; i < 800; i += 256) cnt[i] = 0;
        __syncthreads();

        uint32_t lo[AFIT], hi[AFIT];
        uint16_t rk[AFIT];
        const int base = blockIdx.x * 256 * AFIT;
        #pragma unroll
        for (int k = 0; k < AFIT; ++k) {
            const int e = base + k * 256 + t;
            if (e < N_EDGES) {
                const uint32_t s = (uint32_t)esrc[e];
                const uint32_t d = (uint32_t)edst[e];
                lo[k] = (d << 16) | s;                      // dst:16 | src:16
                hi[k] = __float_as_uint(ew[e]);
                rk[k] = (uint16_t)atomicAdd(&cnt[d >> 6], 1);
            } else {
                lo[k] = 0xffffffffu;
            }
        }
        __syncthreads();
        // reserve global windows (needs cnt before it becomes boff)
        for (int i = t; i < NBKT; i += 256) {
            const int c = cnt[i];
            if (c) wbase[i] = atomicAdd(&cursor[i], c);
        }
        __syncthreads();
        // block-local exclusive scan: cnt[0..799] -> boff (in place)
        int v0[4]; int lsum = 0;
        #pragma unroll
        for (int j = 0; j < 4; ++j) { v0[j] = cnt[t * 4 + j] * ((t * 4 + j) < 800); lsum += v0[j]; }
        // (t*4+j always < 1024; cnt padded to 800 zeros beyond NBKT)
        scr[t] = lsum;
        __syncthreads();
        #pragma unroll
        for (int d = 1; d < 256; d <<= 1) {
            const int a = (t >= d) ? scr[t - d] : 0;
            __syncthreads();
            scr[t] += a;
            __syncthreads();
        }
        int run = scr[t] - lsum;                            // exclusive block prefix
        #pragma unroll
        for (int j = 0; j < 4; ++j) {
            if (t * 4 + j < 800) { const int c = v0[j]; cnt[t * 4 + j] = run; run += c; }
        }
        __syncthreads();
        // scatter into LDS sorted by (bucket, rank)
        #pragma unroll
        for (int k = 0; k < AFIT; ++k) {
            if (lo[k] != 0xffffffffu) {
                const int b = (int)(lo[k] >> 22);           // dst >> 6
                const int i = cnt[b] + (int)rk[k];
                stg[i] = ((uint64_t)hi[k] << 32) | lo[k];
                rkA[i] = rk[k];
            }
        }
        __syncthreads();
        // line-merged output: consecutive i -> consecutive gpos within bucket
        const int total = min(4096, N_EDGES - base);
        for (int i = t; i < total; i += 256) {
            const uint64_t p = stg[i];
            const int b    = (int)((p >> 22) & 0x3ff);      // dst >> 6
            const int gpos = wbase[b] + (int)rkA[i];
            if (gpos < CAP)                                 // overflow guard (P ~ 0)
                pairs[(size_t)b * CAP + gpos] = p;
        }
    } else {
        // ---------------- gemm role (unchanged from R17) ----------------
        float*  wlds = (float*)smem;                    // W [128][32] f32 = 16 KB
        float4* wl4  = (float4*)smem;
        float4* xl4  = (float4*)(smem + 16384);         // x tile [64][33] float4 (+pad)

        const float4* wg4 = reinterpret_cast<const float4*>(w);
        #pragma unroll
        for (int i = 0; i < 4; ++i) wl4[i * 256 + t] = wg4[i * 256 + t];

        const int row0 = (blockIdx.x - FB) * 64;
        const long long gbase4 = (long long)row0 * (K_DIM / 4);
        const long long gmax4  = (long long)N_NODES * (K_DIM / 4);
        const float4* xg4 = reinterpret_cast<const float4*>(x);
        #pragma unroll
        for (int i = 0; i < 8; ++i) {
            const int idx = i * 256 + t;               // 0..2047
            const int row = idx >> 5;
            const int k4  = idx & 31;
            const long long gi = gbase4 + idx;
            xl4[row * 33 + k4] = (gi < gmax4) ? xg4[gi]
                                              : make_float4(0.f, 0.f, 0.f, 0.f);
        }
        __syncthreads();

        const int cg = t & 15;                 // col pair 2cg, 2cg+1
        const int rg = t >> 4;                 // 16 row-groups of 4 rows
        const float2* w2 = reinterpret_cast<const float2*>(wlds);

        float acc[4][2] = {{0.f,0.f},{0.f,0.f},{0.f,0.f},{0.f,0.f}};
        #pragma unroll 4
        for (int k4 = 0; k4 < K_DIM / 4; ++k4) {
            const int k = k4 * 4;
            const float2 wv0 = w2[(k + 0) * 16 + cg];
            const float2 wv1 = w2[(k + 1) * 16 + cg];
            const float2 wv2 = w2[(k + 2) * 16 + cg];
            const float2 wv3 = w2[(k + 3) * 16 + cg];
            #pragma unroll
            for (int r = 0; r < 4; ++r) {
                const float4 xv = xl4[(rg * 4 + r) * 33 + k4];
                acc[r][0] += xv.x * wv0.x + xv.y * wv1.x + xv.z * wv2.x + xv.w * wv3.x;
                acc[r][1] += xv.x * wv0.y + xv.y * wv1.y + xv.z * wv2.y + xv.w * wv3.y;
            }
        }
        uint32_t* h32 = reinterpret_cast<uint32_t*>(h);
        #pragma unroll
        for (int r = 0; r < 4; ++r) {
            const int row = row0 + rg * 4 + r;
            if (row < N_NODES) {
                __hip_bfloat16 b0 = __float2bfloat16(acc[r][0]);
                __hip_bfloat16 b1 = __float2bfloat16(acc[r][1]);
                const uint32_t u0 = *reinterpret_cast<uint16_t*>(&b0);
                const uint32_t u1 = *reinterpret_cast<uint16_t*>(&b1);
                h32[row * 16 + cg] = u0 | (u1 << 16);
            }
        }
    }
}

// -------- K2: sort+pull (R16-proven: reg ranks + wave-parallel scan) --------
__global__ __launch_bounds__(512) void sort_pull(const int*      __restrict__ cursor,
                                                 const uint64_t* __restrict__ pairs,
                                                 const __hip_bfloat16* __restrict__ h,
                                                 float*          __restrict__ out) {
    __shared__ uint64_t stg[CAP];             // 24 KB
    __shared__ int lcnt[64];
    __shared__ int loff[65];
    const int b    = blockIdx.x;
    const int t    = threadIdx.x;
    const size_t beg = (size_t)b * CAP;
    const int cnt  = min(cursor[b], CAP);
    const int wv   = t >> 6;                  // 8 waves
    const int lane = t & 63;
    const int col  = lane & 31;
    const int half = lane >> 5;

    if (t < 64) lcnt[t] = 0;
    __syncthreads();

    uint64_t pl[6];
    int      pr[6];                           // (node<<12)|rank, or -1
    #pragma unroll
    for (int k = 0; k < 6; ++k) {
        const int i = t + k * 512;
        if (i < cnt) {
            const uint64_t p = pairs[beg + i];
            const int nl = (int)((p >> 16) & 63);
            pl[k] = p;
            pr[k] = (nl << 12) | atomicAdd(&lcnt[nl], 1);
        } else {
            pr[k] = -1;
        }
    }
    __syncthreads();
    if (t < 64) {                             // wave-parallel exclusive scan
        const int v = lcnt[t];
        int p = v;
        #pragma unroll
        for (int d = 1; d < 64; d <<= 1) {
            const int n = __shfl_up(p, d, 64);
            if (t >= d) p += n;
        }
        loff[t] = p - v;
        if (t == 63) loff[64] = p;
    }
    __syncthreads();
    #pragma unroll
    for (int k = 0; k < 6; ++k) {
        if (pr[k] >= 0)
            stg[loff[pr[k] >> 12] + (pr[k] & 0xfff)] = pl[k];
    }
    __syncthreads();

    for (int nl = wv * 8; nl < wv * 8 + 8; ++nl) {
        const int node = (b << 6) + nl;
        if (node >= N_NODES) break;
        const int jb = loff[nl], je = loff[nl + 1];
        float acc = 0.f;
        int j = jb + half;
        for (; j + 6 < je; j += 8) {
            const uint64_t p0 = stg[j];
            const uint64_t p1 = stg[j + 2];
            const uint64_t p2 = stg[j + 4];
            const uint64_t p3 = stg[j + 6];
            const float a0 = __bfloat162float(h[(size_t)(p0 & 0xffffu) * OUT_DIM + col]);
            const float a1 = __bfloat162float(h[(size_t)(p1 & 0xffffu) * OUT_DIM + col]);
            const float a2 = __bfloat162float(h[(size_t)(p2 & 0xffffu) * OUT_DIM + col]);
            const float a3 = __bfloat162float(h[(size_t)(p3 & 0xffffu) * OUT_DIM + col]);
            acc += __uint_as_float((uint32_t)(p0 >> 32)) * a0;
            acc += __uint_as_float((uint32_t)(p1 >> 32)) * a1;
            acc += __uint_as_float((uint32_t)(p2 >> 32)) * a2;
            acc += __uint_as_float((uint32_t)(p3 >> 32)) * a3;
        }
        for (; j < je; j += 2) {
            const uint64_t p = stg[j];
            acc += __uint_as_float((uint32_t)(p >> 32)) *
                   __bfloat162float(h[(size_t)(p & 0xffffu) * OUT_DIM + col]);
        }
        acc += __shfl_xor(acc, 32, 64);
        if (half == 0) out[(size_t)node * OUT_DIM + col] = acc;
    }
}

// -------- fallback path kernels (ws too small): plain gemm + atomic scatter -
__global__ __launch_bounds__(256) void gemm_only(const float* __restrict__ x,
                                                 const float* __restrict__ w,
                                                 __hip_bfloat16* __restrict__ h) {
    __shared__ float wlds[K_DIM * OUT_DIM];
    const int t = threadIdx.x;
    #pragma unroll
    for (int i = 0; i < (K_DIM * OUT_DIM) / 256; ++i)
        wlds[i * 256 + t] = w[i * 256 + t];
    __syncthreads();
    const int row = blockIdx.x * 8 + (t >> 5);
    const int col = t & 31;
    if (row >= N_NODES) return;
    const float4* x4 = reinterpret_cast<const float4*>(x + (size_t)row * K_DIM);
    float acc = 0.f;
    #pragma unroll
    for (int k4 = 0; k4 < K_DIM / 4; ++k4) {
        float4 xv = x4[k4];
        const int k = k4 * 4;
        acc += xv.x * wlds[(k + 0) * OUT_DIM + col] + xv.y * wlds[(k + 1) * OUT_DIM + col]
             + xv.z * wlds[(k + 2) * OUT_DIM + col] + xv.w * wlds[(k + 3) * OUT_DIM + col];
    }
    h[(size_t)row * OUT_DIM + col] = __float2bfloat16(acc);
}

__global__ __launch_bounds__(256) void scatter_kernel(const int*   __restrict__ esrc,
                                                      const int*   __restrict__ edst,
                                                      const float* __restrict__ ew,
                                                      const __hip_bfloat16* __restrict__ h,
                                                      float*       out) {
    const long long gid = (long long)blockIdx.x * blockDim.x + threadIdx.x;
    const int e   = (int)(gid >> 5);
    const int col = (int)(gid & 31);
    if (e >= N_EDGES) return;
    atomicAdd(out + (size_t)edst[e] * OUT_DIM + col,
              ew[e] * __bfloat162float(h[(size_t)esrc[e] * OUT_DIM + col]));
}

extern "C" void kernel_launch(void* const* d_in, const int* in_sizes, int n_in,
                              void* d_out, int out_size, void* d_ws, size_t ws_size,
                              hipStream_t stream) {
    const float* x    = (const float*)d_in[0];
    const float* w    = (const float*)d_in[1];
    const int*   esrc = (const int*)d_in[2];
    const int*   edst = (const int*)d_in[3];
    const float* ew   = (const float*)d_in[4];
    float*       out  = (float*)d_out;

    const size_t PAIRS_B = (size_t)NBKT * CAP * 8;         // 19,218,432
    const size_t H_B     = (size_t)N_NODES * OUT_DIM * 2;  //  3,200,000 (bf16)
    const size_t CUR_B   = (size_t)NBKT * 4;               //      3,128
    const size_t REQ     = PAIRS_B + H_B + CUR_B;

    uint64_t*        pairs  = (uint64_t*)d_ws;
    __hip_bfloat16*  h      = (__hip_bfloat16*)((char*)d_ws + PAIRS_B);
    int*             cursor = (int*)((char*)d_ws + PAIRS_B + H_B);

    if (ws_size >= REQ) {
        zero_cursor<<<1, 256, 0, stream>>>(cursor);
        gemm_fill<<<FB + GB, 256, 0, stream>>>(x, w, h, esrc, edst, ew, cursor, pairs);
        sort_pull<<<NBKT, 512, 0, stream>>>(cursor, pairs, h, out);
    } else {
        __hip_bfloat16* hf = (__hip_bfloat16*)d_ws;
        (void)hipMemsetAsync(d_out, 0, (size_t)out_size * sizeof(float), stream);
        gemm_only<<<(N_NODES + 7) / 8, 256, 0, stream>>>(x, w, hf);
        const long long total = (long long)N_EDGES * OUT_DIM;
        scatter_kernel<<<(int)((total + 255) / 256), 256, 0, stream>>>(esrc, edst, ew, hf, out);
    }
}